// Round 6
// baseline (7591.386 us; speedup 1.0000x reference)
//
#include <hip/hip_runtime.h>
#include <math.h>

// Problem constants (GridSmoother)
#define B_   16
#define P_   8192
#define N_   1024
#define D_   384
#define L_   12
#define H_   6
#define HD_  64
#define M_   (B_*N_)     // 16384 rows
#define DQKV_ (3*D_)     // 1152
#define DH_   (4*D_)     // 1536

typedef unsigned short ushort_t;
typedef unsigned long long u64_t;
typedef __attribute__((ext_vector_type(8))) short short8;
typedef __attribute__((ext_vector_type(4))) float floatx4;

// bf16 helpers (RNE), raw-bits representation
__device__ __forceinline__ ushort_t f2bf(float f) {
    unsigned u = __float_as_uint(f);
    unsigned rounding = 0x7fffu + ((u >> 16) & 1u);
    return (ushort_t)((u + rounding) >> 16);
}
__device__ __forceinline__ float bf2f(ushort_t u) {
    return __uint_as_float(((unsigned)u) << 16);
}

// ---------------------------------------------------------------------------
// Embed: X[m,d] = sum_k grid[m,k] * ew[k,d]   (K=3)
__global__ __launch_bounds__(D_) void embed_kernel(const float* __restrict__ g,
                                                   const float* __restrict__ ew,
                                                   float* __restrict__ X) {
    int m = blockIdx.x;
    int d = threadIdx.x;
    float g0 = g[m*3+0], g1 = g[m*3+1], g2 = g[m*3+2];
    X[(size_t)m*D_ + d] = g0*ew[0*D_+d] + g1*ew[1*D_+d] + g2*ew[2*D_+d];
}

// ---------------------------------------------------------------------------
// Weight transpose-cast: W [L][K][N] f32 -> Wt [L][N][K] bf16 bits
__global__ __launch_bounds__(256) void transcast_kernel(const float* __restrict__ W,
                                                        ushort_t* __restrict__ Wt,
                                                        int K, int Nc) {
    __shared__ float t[32][33];
    const float* Wl = W + (size_t)blockIdx.z*K*Nc;
    ushort_t* Wtl = Wt + (size_t)blockIdx.z*K*Nc;
    int n0 = blockIdx.x*32, k0 = blockIdx.y*32;
    int tx = threadIdx.x & 31, ty = threadIdx.x >> 5;   // 32 x 8
#pragma unroll
    for (int j = 0; j < 32; j += 8)
        t[ty+j][tx] = Wl[(size_t)(k0+ty+j)*Nc + n0+tx];
    __syncthreads();
#pragma unroll
    for (int j = 0; j < 32; j += 8)
        Wtl[(size_t)(n0+ty+j)*K + k0+tx] = f2bf(t[tx][ty+j]);
}

// ---------------------------------------------------------------------------
// LayerNorm: one wave per row of 384; reads f32 X, writes bf16 bits.
__global__ __launch_bounds__(256) void ln_kernel(const float* __restrict__ Xin,
                                                 const float* __restrict__ w,
                                                 const float* __restrict__ bvec,
                                                 ushort_t* __restrict__ out) {
    int wid = threadIdx.x >> 6, lane = threadIdx.x & 63;
    int row = blockIdx.x*4 + wid;
    const float* xr = Xin + (size_t)row*D_;
    float v[6];
#pragma unroll
    for (int i = 0; i < 6; i++) v[i] = xr[lane + i*64];
    float s = 0.f;
#pragma unroll
    for (int i = 0; i < 6; i++) s += v[i];
#pragma unroll
    for (int off = 32; off; off >>= 1) s += __shfl_xor(s, off, 64);
    float mean = s * (1.0f/(float)D_);
    float vs = 0.f;
#pragma unroll
    for (int i = 0; i < 6; i++) { float d = v[i]-mean; vs += d*d; }
#pragma unroll
    for (int off = 32; off; off >>= 1) vs += __shfl_xor(vs, off, 64);
    float var = vs * (1.0f/(float)D_);
    float rstd = 1.0f / sqrtf(var + 1e-5f);
    ushort_t* orow = out + (size_t)row*D_;
#pragma unroll
    for (int i = 0; i < 6; i++) {
        int e = lane + i*64;
        orow[e] = f2bf((v[i]-mean)*rstd*w[e] + bvec[e]);
    }
}

// ---------------------------------------------------------------------------
__device__ __forceinline__ float gelu_f(float x) {
    const float c = 0.7978845608028654f;   // sqrt(2/pi)
    float x3 = x*x*x;
    return 0.5f*x*(1.0f + tanhf(c*(x + 0.044715f*x3)));
}

// ---------------------------------------------------------------------------
// MFMA bf16 GEMM v2.1: register-prefetch staging; LDS stride 34 (conflict fix);
// vectorized epilogues. C[M,Nc] = A[M,K] @ Wt[Nc,K]^T + bias.
// EPI: 0 = bias -> bf16 out; 1 = bias + residual add into f32 C;
//      2 = gelu(bias+acc) -> bf16 out;
//      3 = QKV split: cols<768 packed bf16, cols>=768 scatter to VT.
#define GS_ 34
template<int EPI>
__global__ __launch_bounds__(256) void mfma_gemm(const ushort_t* __restrict__ A,
                                                 const ushort_t* __restrict__ Wt,
                                                 const float* __restrict__ bias,
                                                 void* __restrict__ Cout,
                                                 ushort_t* __restrict__ VT,
                                                 int K, int Nc) {
    __shared__ __attribute__((aligned(16))) ushort_t smem[2*128*GS_];   // ~17.4 KB
    ushort_t* smA = smem;
    ushort_t* smB = smem + 128*GS_;
    int tid = threadIdx.x;
    int lane = tid & 63, w = tid >> 6;
    int wm = w >> 1, wn = w & 1;
    int L = lane & 15, G = lane >> 4;
    int rowBase = blockIdx.y * 128, colBase = blockIdx.x * 128;

    floatx4 acc[4][4];
#pragma unroll
    for (int i = 0; i < 4; i++)
#pragma unroll
        for (int j = 0; j < 4; j++) acc[i][j] = (floatx4){0.f,0.f,0.f,0.f};

    // staging map: 256 threads x 2 chunks per buffer; chunk = 16B = 8 bf16
    int sr = tid >> 2;          // row 0..63 (and +64)
    int kc = tid & 3;           // k-chunk 0..3
    const ushort_t* Ag = A  + (size_t)(rowBase + sr)*K + kc*8;
    const ushort_t* Bg = Wt + (size_t)(colBase + sr)*K + kc*8;
    size_t step64 = (size_t)64*K;

    short8 ra0, ra1, rb0, rb1;
    ra0 = *(const short8*)(Ag);
    ra1 = *(const short8*)(Ag + step64);
    rb0 = *(const short8*)(Bg);
    rb1 = *(const short8*)(Bg + step64);

    for (int k0 = 0; k0 < K; k0 += 32) {
        __syncthreads();
        *(short8*)(smA + sr*GS_ + kc*8)        = ra0;
        *(short8*)(smA + (64+sr)*GS_ + kc*8)   = ra1;
        *(short8*)(smB + sr*GS_ + kc*8)        = rb0;
        *(short8*)(smB + (64+sr)*GS_ + kc*8)   = rb1;
        __syncthreads();
        if (k0 + 32 < K) {      // prefetch next k-slab
            ra0 = *(const short8*)(Ag + k0 + 32);
            ra1 = *(const short8*)(Ag + step64 + k0 + 32);
            rb0 = *(const short8*)(Bg + k0 + 32);
            rb1 = *(const short8*)(Bg + step64 + k0 + 32);
        }
        short8 af[4], bfr[4];
#pragma unroll
        for (int t = 0; t < 4; t++) {
            af[t]  = *(const short8*)(smA + (wm*64 + t*16 + L)*GS_ + G*8);
            bfr[t] = *(const short8*)(smB + (wn*64 + t*16 + L)*GS_ + G*8);
        }
#pragma unroll
        for (int mt = 0; mt < 4; mt++)
#pragma unroll
            for (int nt = 0; nt < 4; nt++)
                acc[mt][nt] = __builtin_amdgcn_mfma_f32_16x16x32_bf16(
                    af[mt], bfr[nt], acc[mt][nt], 0, 0, 0);
        __syncthreads();
    }

    __syncthreads();   // smem reuse for epilogue

    if (EPI == 3 && colBase >= 2*D_) {
        // pure-V column block: scalar scatter into VT[b,h,d,n]
        int cBase = colBase + wn*64 + L;
        int rBase = rowBase + wm*64 + G*4;
#pragma unroll
        for (int nt = 0; nt < 4; nt++) {
            int col = cBase + nt*16;
            float bv = bias[col];
            int hh = (col - 2*D_) >> 6, d = (col - 2*D_) & 63;
#pragma unroll
            for (int mt = 0; mt < 4; mt++) {
#pragma unroll
                for (int r = 0; r < 4; r++) {
                    int row = rBase + mt*16 + r;
                    int b = row >> 10, n = row & 1023;
                    VT[(((size_t)b*H_ + hh)*64 + d)*N_ + n] = f2bf(acc[mt][nt][r] + bv);
                }
            }
        }
    } else if (EPI == 1) {
        // f32 residual add, vectorized via per-wave LDS slab (16x64 f32)
        float* fs = (float*)smem + w*1024;
        int orow = lane >> 2, c4 = lane & 3;
#pragma unroll
        for (int mt = 0; mt < 4; mt++) {
#pragma unroll
            for (int nt = 0; nt < 4; nt++) {
                float bv = bias[colBase + wn*64 + nt*16 + L];
#pragma unroll
                for (int r = 0; r < 4; r++)
                    fs[(G*4+r)*64 + nt*16 + L] = acc[mt][nt][r] + bv;
            }
            float* og = (float*)Cout + (size_t)(rowBase + wm*64 + mt*16 + orow)*Nc
                        + colBase + wn*64;
#pragma unroll
            for (int kk = 0; kk < 4; kk++) {
                float4 sv = *(float4*)(fs + orow*64 + kk*16 + c4*4);
                float4 gv = *(float4*)(og + kk*16 + c4*4);
                gv.x += sv.x; gv.y += sv.y; gv.z += sv.z; gv.w += sv.w;
                *(float4*)(og + kk*16 + c4*4) = gv;
            }
        }
    } else {
        // bf16 out (EPI 0/2/3-QK), vectorized via per-wave LDS slab (stride 72)
        ushort_t* us = smem + w*1152;
        int orow = lane >> 2, oc = lane & 3;
#pragma unroll
        for (int mt = 0; mt < 4; mt++) {
#pragma unroll
            for (int nt = 0; nt < 4; nt++) {
                float bv = bias[colBase + wn*64 + nt*16 + L];
#pragma unroll
                for (int r = 0; r < 4; r++) {
                    float v = acc[mt][nt][r] + bv;
                    if (EPI == 2) v = gelu_f(v);
                    us[(G*4+r)*72 + nt*16 + L] = f2bf(v);
                }
            }
            short8 o0 = *(short8*)(us + orow*72 + oc*8);
            short8 o1 = *(short8*)(us + orow*72 + 32 + oc*8);
            ushort_t* og = (ushort_t*)Cout + (size_t)(rowBase + wm*64 + mt*16 + orow)*Nc
                           + colBase + wn*64;
            *(short8*)(og + oc*8) = o0;
            *(short8*)(og + 32 + oc*8) = o1;
        }
    }
}

// ---------------------------------------------------------------------------
// Flash attention v3 (MFMA): 128-key tiles, register-prefetch staging,
// 2 barriers per 128 keys, XCD-swizzled 1D grid (K/V L2 locality),
// conflict-reduced LDS strides.
#define KS_ 66     // Ks row stride  (64 d + 2)
#define VS_ 130    // Vs/Pw row stride (128 keys + 2)
__global__ __launch_bounds__(256) void fattn_kernel(const ushort_t* __restrict__ QKV,
                                                    const ushort_t* __restrict__ VT,
                                                    ushort_t* __restrict__ O) {
    __shared__ __attribute__((aligned(16))) ushort_t Ks[128*KS_];   // [key][d]
    __shared__ __attribute__((aligned(16))) ushort_t Vs[64*VS_];    // [d][key]
    __shared__ __attribute__((aligned(16))) ushort_t Pw[4*16*VS_];
    // XCD swizzle: all 16 q-blocks of one (b,h) on one XCD (xcd = blk % 8 heuristic)
    int blk = blockIdx.x;
    int xcd = blk & 7, idx = blk >> 3;
    int bh = xcd*12 + (idx >> 4);
    int qb = idx & 15;
    int b = bh / H_, h = bh % H_;
    int qBase = qb * 64;
    int tid = threadIdx.x;
    int lane = tid & 63, w = tid >> 6;
    int L = lane & 15, G = lane >> 4;

    short8 qf[2];
    {
        const ushort_t* qp = QKV + ((size_t)(b*N_ + qBase + w*16 + L))*DQKV_ + h*HD_ + G*8;
        qf[0] = *(const short8*)(qp);
        qf[1] = *(const short8*)(qp + 32);
    }

    floatx4 oacc[4];
#pragma unroll
    for (int nt = 0; nt < 4; nt++) oacc[nt] = (floatx4){0.f,0.f,0.f,0.f};
    float mrow[4], lrow[4];
#pragma unroll
    for (int r = 0; r < 4; r++) { mrow[r] = -3.0e38f; lrow[r] = 0.f; }

    ushort_t* pw = Pw + w*16*VS_;
    const ushort_t* Kbase = QKV + (size_t)b*N_*DQKV_ + D_ + h*HD_;
    const ushort_t* Vbase = VT + ((size_t)b*H_ + h)*64*N_;

    // staging: K tile 128x64 (1024 chunks), V^T tile 64x128 (1024 chunks);
    // thread covers chunks tid+256*i, i<4.  K: key=c>>3, dc=c&7.  V: d=c>>4, kc=c&15.
    short8 rk[4], rv[4];
#pragma unroll
    for (int i = 0; i < 4; i++) {
        int c = tid + 256*i;
        rk[i] = *(const short8*)(Kbase + (size_t)(c>>3)*DQKV_ + (c&7)*8);
        rv[i] = *(const short8*)(Vbase + (size_t)(c>>4)*N_ + (c&15)*8);
    }

    for (int kt = 0; kt < N_/128; kt++) {
        __syncthreads();   // prior tile fully consumed
#pragma unroll
        for (int i = 0; i < 4; i++) {
            int c = tid + 256*i;
            *(short8*)(Ks + (c>>3)*KS_ + (c&7)*8)  = rk[i];
            *(short8*)(Vs + (c>>4)*VS_ + (c&15)*8) = rv[i];
        }
        __syncthreads();
        if (kt + 1 < N_/128) {   // prefetch next tile (in flight across compute)
#pragma unroll
            for (int i = 0; i < 4; i++) {
                int c = tid + 256*i;
                rk[i] = *(const short8*)(Kbase + (size_t)((kt+1)*128 + (c>>3))*DQKV_ + (c&7)*8);
                rv[i] = *(const short8*)(Vbase + (size_t)(c>>4)*N_ + (kt+1)*128 + (c&15)*8);
            }
        }

        // S = Q K^T  (16 q-rows x 128 keys per wave)
        floatx4 sc[8];
#pragma unroll
        for (int ct = 0; ct < 8; ct++) sc[ct] = (floatx4){0.f,0.f,0.f,0.f};
#pragma unroll
        for (int ks = 0; ks < 2; ks++)
#pragma unroll
            for (int ct = 0; ct < 8; ct++) {
                short8 bf = *(const short8*)(Ks + (ct*16 + L)*KS_ + ks*32 + G*8);
                sc[ct] = __builtin_amdgcn_mfma_f32_16x16x32_bf16(qf[ks], bf, sc[ct], 0, 0, 0);
            }

        // online softmax over this 128-key tile
        float rmax[4], rsum[4];
#pragma unroll
        for (int r = 0; r < 4; r++) {
            float mx = sc[0][r];
#pragma unroll
            for (int ct = 0; ct < 8; ct++) { sc[ct][r] *= 0.125f; }
            mx = sc[0][r];
#pragma unroll
            for (int ct = 1; ct < 8; ct++) mx = fmaxf(mx, sc[ct][r]);
            rmax[r] = mx;
        }
#pragma unroll
        for (int off = 1; off < 16; off <<= 1)
#pragma unroll
            for (int r = 0; r < 4; r++) rmax[r] = fmaxf(rmax[r], __shfl_xor(rmax[r], off, 64));
        float corr[4];
#pragma unroll
        for (int r = 0; r < 4; r++) {
            float mn = fmaxf(mrow[r], rmax[r]);
            corr[r] = __expf(mrow[r] - mn);
            mrow[r] = mn;
            rsum[r] = 0.f;
#pragma unroll
            for (int ct = 0; ct < 8; ct++) {
                float p = __expf(sc[ct][r] - mn);
                sc[ct][r] = p;
                rsum[r] += p;
            }
        }
#pragma unroll
        for (int off = 1; off < 16; off <<= 1)
#pragma unroll
            for (int r = 0; r < 4; r++) rsum[r] += __shfl_xor(rsum[r], off, 64);
#pragma unroll
        for (int r = 0; r < 4; r++) lrow[r] = lrow[r]*corr[r] + rsum[r];

        // P (C-layout) -> wave-private LDS -> A-layout (in-wave ordering, no barrier)
#pragma unroll
        for (int ct = 0; ct < 8; ct++)
#pragma unroll
            for (int r = 0; r < 4; r++)
                pw[(G*4 + r)*VS_ + ct*16 + L] = f2bf(sc[ct][r]);
#pragma unroll
        for (int nt = 0; nt < 4; nt++)
#pragma unroll
            for (int r = 0; r < 4; r++) oacc[nt][r] *= corr[r];

        // O += P V   (K = 128 -> 4 k-steps)
#pragma unroll
        for (int ks = 0; ks < 4; ks++) {
            short8 pf = *(const short8*)(pw + L*VS_ + ks*32 + G*8);
#pragma unroll
            for (int nt = 0; nt < 4; nt++) {
                short8 vf = *(const short8*)(Vs + (nt*16 + L)*VS_ + ks*32 + G*8);
                oacc[nt] = __builtin_amdgcn_mfma_f32_16x16x32_bf16(pf, vf, oacc[nt], 0, 0, 0);
            }
        }
    }

    // normalized O through wave-private pw slab -> vector global store
    float inv[4];
#pragma unroll
    for (int r = 0; r < 4; r++) inv[r] = 1.0f / lrow[r];
#pragma unroll
    for (int nt = 0; nt < 4; nt++)
#pragma unroll
        for (int r = 0; r < 4; r++)
            pw[(G*4 + r)*VS_ + nt*16 + L] = f2bf(oacc[nt][r]*inv[r]);
    int orow = lane >> 2, oc = lane & 3;
    short8 o0 = *(short8*)(pw + orow*VS_ + oc*8);
    short8 o1 = *(short8*)(pw + orow*VS_ + 32 + oc*8);
    ushort_t* og = O + (size_t)(b*N_ + qBase + w*16 + orow)*D_ + h*HD_;
    *(short8*)(og + oc*8) = o0;
    *(short8*)(og + 32 + oc*8) = o1;
}

// ---------------------------------------------------------------------------
// Final projection v2: one wave per row (coalesced); pred[m,c] = X[m,:] @ pw[:,c]
__global__ __launch_bounds__(256) void proj_kernel(const float* __restrict__ X,
                                                   const float* __restrict__ pw,
                                                   float* __restrict__ pred) {
    int wid = threadIdx.x >> 6, lane = threadIdx.x & 63;
    int m = blockIdx.x*4 + wid;
    const float* xr = X + (size_t)m*D_;
    float a0 = 0.f, a1 = 0.f, a2 = 0.f;
#pragma unroll
    for (int i = 0; i < 6; i++) {
        int k = lane + i*64;
        float xv = xr[k];
        a0 += xv*pw[k*3+0]; a1 += xv*pw[k*3+1]; a2 += xv*pw[k*3+2];
    }
#pragma unroll
    for (int off = 32; off; off >>= 1) {
        a0 += __shfl_xor(a0, off, 64);
        a1 += __shfl_xor(a1, off, 64);
        a2 += __shfl_xor(a2, off, 64);
    }
    if (lane == 0) {
        pred[m*3+0] = a0; pred[m*3+1] = a1; pred[m*3+2] = a2;
    }
}

// ---------------------------------------------------------------------------
// FPS v4: 512 threads (8 waves), 16 pts/thread in registers, pts mirrored in
// LDS for winner-coordinate broadcast. One barrier/iter; DS-traffic-minimized:
// per-thread (f32,j) best -> single u64 pack -> 6-round wave reduce ->
// lane-indexed slot read + 3-round in-wave merge (vs flat 16-read merge).
__global__ __launch_bounds__(512) void fps_kernel(const float* __restrict__ pts,
                                                  float* __restrict__ centers) {
    __shared__ float Lx[P_], Ly[P_], Lz[P_];            // 96 KiB
    __shared__ u64_t slot[2][8];
    int b = blockIdx.x, t = threadIdx.x;
    const float* pb = pts + (size_t)b*P_*3;
    float px[16], py[16], pz[16], dist[16];
#pragma unroll
    for (int j = 0; j < 16; j++) {
        int p = j*512 + t;
        px[j] = pb[p*3+0]; py[j] = pb[p*3+1]; pz[j] = pb[p*3+2];
        Lx[p] = px[j]; Ly[p] = py[j]; Lz[p] = pz[j];
        dist[j] = 1e10f;
    }
    int wid = t >> 6, lane = t & 63;
    int winner = 0;
    __syncthreads();
    for (int it = 0; it < N_; it++) {
        float lx = Lx[winner], ly = Ly[winner], lz = Lz[winner];
        if (t == 0) {
            float* c = centers + ((size_t)b*N_ + it)*3;
            c[0] = lx; c[1] = ly; c[2] = lz;
        }
        // per-thread best: strict > with ascending j == smallest index on ties
        float bd = -1.0f; int bj = 0;
#pragma unroll
        for (int j = 0; j < 16; j++) {
            float dx = __fsub_rn(px[j], lx);
            float dy = __fsub_rn(py[j], ly);
            float dz = __fsub_rn(pz[j], lz);
            float d = __fadd_rn(__fadd_rn(__fmul_rn(dx,dx), __fmul_rn(dy,dy)), __fmul_rn(dz,dz));
            d = fminf(dist[j], d);
            dist[j] = d;
            bool gt = d > bd;
            bd = gt ? d : bd;
            bj = gt ? j : bj;
        }
        // pack once: global idx = bj*512 + t (ascending in j), ~idx -> first-wins
        u64_t best = ((u64_t)__float_as_uint(bd) << 32)
                   | (unsigned)(~(unsigned)(bj*512 + t));
#pragma unroll
        for (int off = 32; off; off >>= 1) {
            u64_t o = __shfl_xor(best, off, 64);
            best = (o > best) ? o : best;
        }
        int par = it & 1;
        if (lane == 0) slot[par][wid] = best;
        __syncthreads();
        // merge 8 wave maxima: lane-indexed read + 3 xor rounds (all lanes agree)
        u64_t v = slot[par][lane & 7];
#pragma unroll
        for (int off = 1; off < 8; off <<= 1) {
            u64_t o = __shfl_xor(v, off, 64);
            v = (o > v) ? o : v;
        }
        winner = (int)(~(unsigned)(v & 0xFFFFFFFFull));
    }
}

// ---------------------------------------------------------------------------
__global__ __launch_bounds__(256) void nnmin_kernel(const float* __restrict__ Asrc,
                                                    const float* __restrict__ Bsrc,
                                                    float* __restrict__ outmin) {
    int b = blockIdx.y;
    int i = blockIdx.x*256 + threadIdx.x;
    __shared__ float tile[256][3];
    const float* ar = Asrc + ((size_t)b*N_ + i)*3;
    float ax = ar[0], ay = ar[1], az = ar[2];
    float best = 3.0e38f;
    for (int j0 = 0; j0 < N_; j0 += 256) {
        __syncthreads();
        const float* br = Bsrc + ((size_t)b*N_ + j0 + threadIdx.x)*3;
        tile[threadIdx.x][0] = br[0]; tile[threadIdx.x][1] = br[1]; tile[threadIdx.x][2] = br[2];
        __syncthreads();
        for (int j = 0; j < 256; j++) {
            float dx = ax - tile[j][0], dy = ay - tile[j][1], dz = az - tile[j][2];
            float d = dx*dx + dy*dy + dz*dz;
            best = fminf(best, d);
        }
    }
    outmin[(size_t)b*N_ + i] = sqrtf(best);
}

__global__ __launch_bounds__(256) void knn_kernel(const float* __restrict__ Pp,
                                                  float* __restrict__ mean_d) {
    int b = blockIdx.y;
    int i = blockIdx.x*256 + threadIdx.x;
    __shared__ float tile[256][3];
    const float* ar = Pp + ((size_t)b*N_ + i)*3;
    float ax = ar[0], ay = ar[1], az = ar[2];
    float s[6];
#pragma unroll
    for (int q = 0; q < 6; q++) s[q] = 3.0e38f;
    for (int j0 = 0; j0 < N_; j0 += 256) {
        __syncthreads();
        const float* br = Pp + ((size_t)b*N_ + j0 + threadIdx.x)*3;
        tile[threadIdx.x][0] = br[0]; tile[threadIdx.x][1] = br[1]; tile[threadIdx.x][2] = br[2];
        __syncthreads();
        for (int j = 0; j < 256; j++) {
            float dx = ax - tile[j][0], dy = ay - tile[j][1], dz = az - tile[j][2];
            float d = dx*dx + dy*dy + dz*dz;
            if (d < s[5]) {
                s[5] = d;
#pragma unroll
                for (int q = 5; q > 0; q--)
                    if (s[q] < s[q-1]) { float tmp = s[q]; s[q] = s[q-1]; s[q-1] = tmp; }
            }
        }
    }
    float msum = sqrtf(s[1]) + sqrtf(s[2]) + sqrtf(s[3]) + sqrtf(s[4]) + sqrtf(s[5]);
    mean_d[(size_t)b*N_ + i] = msum * 0.2f;
}

__global__ __launch_bounds__(256) void kl_kernel(const float* __restrict__ md,
                                                 float* __restrict__ klb) {
    int b = blockIdx.x, t = threadIdx.x;
    const float* row = md + (size_t)b*N_;
    float v[4];
#pragma unroll
    for (int i = 0; i < 4; i++) v[i] = row[t + i*256];
    float mx = fmaxf(fmaxf(v[0], v[1]), fmaxf(v[2], v[3]));
#pragma unroll
    for (int off = 32; off; off >>= 1) mx = fmaxf(mx, __shfl_xor(mx, off, 64));
    __shared__ float redm[4], rse[4], rsx[4];
    int wid = t >> 6, lane = t & 63;
    if (lane == 0) redm[wid] = mx;
    __syncthreads();
    mx = fmaxf(fmaxf(redm[0], redm[1]), fmaxf(redm[2], redm[3]));
    float se = 0.f, sx = 0.f;
#pragma unroll
    for (int i = 0; i < 4; i++) { se += expf(v[i]-mx); sx += v[i]; }
#pragma unroll
    for (int off = 32; off; off >>= 1) { se += __shfl_xor(se, off, 64); sx += __shfl_xor(sx, off, 64); }
    if (lane == 0) { rse[wid] = se; rsx[wid] = sx; }
    __syncthreads();
    if (t == 0) {
        float SE = rse[0]+rse[1]+rse[2]+rse[3];
        float SX = rsx[0]+rsx[1]+rsx[2]+rsx[3];
        klb[b] = mx + logf(SE) - SX*(1.0f/(float)N_) - logf((float)N_);
    }
}

__global__ __launch_bounds__(256) void final_kernel(const float* __restrict__ rma,
                                                    const float* __restrict__ rmb,
                                                    const float* __restrict__ klb,
                                                    float* __restrict__ out) {
    int t = threadIdx.x;
    float s = 0.f;
    for (int i = t; i < B_*N_; i += 256) s += rma[i] + rmb[i];
#pragma unroll
    for (int off = 32; off; off >>= 1) s += __shfl_xor(s, off, 64);
    __shared__ float red[4];
    int wid = t >> 6, lane = t & 63;
    if (lane == 0) red[wid] = s;
    __syncthreads();
    if (t == 0) {
        float S = red[0]+red[1]+red[2]+red[3];
        out[0] = 0.5f*S/(float)(B_*N_);
        float K = 0.f;
        for (int b = 0; b < B_; b++) K += klb[b];
        out[1] = K/(float)B_;
    }
}

// ---------------------------------------------------------------------------
extern "C" void kernel_launch(void* const* d_in, const int* in_sizes, int n_in,
                              void* d_out, int out_size, void* d_ws, size_t ws_size,
                              hipStream_t stream) {
    (void)in_sizes; (void)n_in; (void)out_size; (void)ws_size;
    const float* pts     = (const float*)d_in[0];
    const float* grid    = (const float*)d_in[1];
    const float* embed_w = (const float*)d_in[2];
    const float* proj_w  = (const float*)d_in[3];
    const float* ln1_w   = (const float*)d_in[4];
    const float* ln1_b   = (const float*)d_in[5];
    const float* qkv_w   = (const float*)d_in[6];
    const float* qkv_b   = (const float*)d_in[7];
    const float* attn_w  = (const float*)d_in[8];
    const float* attn_b  = (const float*)d_in[9];
    const float* ln2_w   = (const float*)d_in[10];
    const float* ln2_b   = (const float*)d_in[11];
    const float* mlp_w1  = (const float*)d_in[12];
    const float* mlp_b1  = (const float*)d_in[13];
    const float* mlp_w2  = (const float*)d_in[14];
    const float* mlp_b2  = (const float*)d_in[15];
    float* out = (float*)d_out;

    // workspace layout (~144 MB)
    float*    X     = (float*)d_ws;                         // M*D f32
    ushort_t* Hb16  = (ushort_t*)(X + (size_t)M_*D_);       // M*D bf16
    ushort_t* BIG16 = Hb16 + (size_t)M_*D_;                 // M*1536 bf16 (QKV / MLP hidden)
    ushort_t* VT    = BIG16 + (size_t)M_*DH_;               // B*H*64*N bf16 (V transposed)
    ushort_t* WQ    = VT  + (size_t)B_*H_*HD_*N_;           // L*1152*384
    ushort_t* WA    = WQ  + (size_t)L_*DQKV_*D_;            // L*384*384
    ushort_t* WM1   = WA  + (size_t)L_*D_*D_;               // L*1536*384
    ushort_t* WM2   = WM1 + (size_t)L_*DH_*D_;              // L*384*1536
    float*    PRED  = (float*)(WM2 + (size_t)L_*D_*DH_);    // M*3
    float*    CENT  = PRED + (size_t)M_*3;                  // B*N*3
    float*    RMA   = CENT + (size_t)B_*N_*3;               // B*N
    float*    RMB   = RMA  + (size_t)B_*N_;                 // B*N
    float*    MEAND = RMB  + (size_t)B_*N_;                 // B*N
    float*    KLB   = MEAND + (size_t)B_*N_;                // B

    // one-time weight transpose-casts (f32 [K,N] -> bf16 [N,K])
    transcast_kernel<<<dim3(DQKV_/32, D_/32,  L_), 256, 0, stream>>>(qkv_w,  WQ,  D_,  DQKV_);
    transcast_kernel<<<dim3(D_/32,    D_/32,  L_), 256, 0, stream>>>(attn_w, WA,  D_,  D_);
    transcast_kernel<<<dim3(DH_/32,   D_/32,  L_), 256, 0, stream>>>(mlp_w1, WM1, D_,  DH_);
    transcast_kernel<<<dim3(D_/32,    DH_/32, L_), 256, 0, stream>>>(mlp_w2, WM2, DH_, D_);

    // FPS (independent of transformer)
    fps_kernel<<<B_, 512, 0, stream>>>(pts, CENT);

    embed_kernel<<<M_, D_, 0, stream>>>(grid, embed_w, X);

    for (int l = 0; l < L_; l++) {
        ln_kernel<<<M_/4, 256, 0, stream>>>(X, ln1_w + l*D_, ln1_b + l*D_, Hb16);
        mfma_gemm<3><<<dim3(DQKV_/128, M_/128), 256, 0, stream>>>(
            Hb16, WQ + (size_t)l*DQKV_*D_, qkv_b + l*DQKV_, BIG16, VT, D_, DQKV_);
        fattn_kernel<<<(N_/64)*H_*B_, 256, 0, stream>>>(BIG16, VT, Hb16);
        mfma_gemm<1><<<dim3(D_/128, M_/128), 256, 0, stream>>>(
            Hb16, WA + (size_t)l*D_*D_, attn_b + l*D_, X, nullptr, D_, D_);
        ln_kernel<<<M_/4, 256, 0, stream>>>(X, ln2_w + l*D_, ln2_b + l*D_, Hb16);
        mfma_gemm<2><<<dim3(DH_/128, M_/128), 256, 0, stream>>>(
            Hb16, WM1 + (size_t)l*DH_*D_, mlp_b1 + l*DH_, BIG16, nullptr, D_, DH_);
        mfma_gemm<1><<<dim3(D_/128, M_/128), 256, 0, stream>>>(
            BIG16, WM2 + (size_t)l*D_*DH_, mlp_b2 + l*D_, X, nullptr, DH_, D_);
    }

    proj_kernel<<<M_/4, 256, 0, stream>>>(X, proj_w, PRED);

    nnmin_kernel<<<dim3(N_/256, B_), 256, 0, stream>>>(PRED, CENT, RMA);
    nnmin_kernel<<<dim3(N_/256, B_), 256, 0, stream>>>(CENT, PRED, RMB);
    knn_kernel<<<dim3(N_/256, B_), 256, 0, stream>>>(PRED, MEAND);
    kl_kernel<<<B_, 256, 0, stream>>>(MEAND, KLB);
    final_kernel<<<1, 256, 0, stream>>>(RMA, RMB, KLB, out);
}

// Round 7
// 4618.832 us; speedup vs baseline: 1.6436x; 1.6436x over previous
//
#include <hip/hip_runtime.h>
#include <math.h>

// Problem constants (GridSmoother)
#define B_   16
#define P_   8192
#define N_   1024
#define D_   384
#define L_   12
#define H_   6
#define HD_  64
#define M_   (B_*N_)     // 16384 rows
#define DQKV_ (3*D_)     // 1152
#define DH_   (4*D_)     // 1536

typedef unsigned short ushort_t;
typedef unsigned long long u64_t;
typedef __attribute__((ext_vector_type(8))) short short8;
typedef __attribute__((ext_vector_type(4))) float floatx4;

// bf16 helpers (RNE), raw-bits representation
__device__ __forceinline__ ushort_t f2bf(float f) {
    unsigned u = __float_as_uint(f);
    unsigned rounding = 0x7fffu + ((u >> 16) & 1u);
    return (ushort_t)((u + rounding) >> 16);
}
__device__ __forceinline__ float bf2f(ushort_t u) {
    return __uint_as_float(((unsigned)u) << 16);
}

// ---------------------------------------------------------------------------
// Embed: X[m,d] = sum_k grid[m,k] * ew[k,d]   (K=3)
__global__ __launch_bounds__(D_) void embed_kernel(const float* __restrict__ g,
                                                   const float* __restrict__ ew,
                                                   float* __restrict__ X) {
    int m = blockIdx.x;
    int d = threadIdx.x;
    float g0 = g[m*3+0], g1 = g[m*3+1], g2 = g[m*3+2];
    X[(size_t)m*D_ + d] = g0*ew[0*D_+d] + g1*ew[1*D_+d] + g2*ew[2*D_+d];
}

// ---------------------------------------------------------------------------
// Weight transpose-cast: W [L][K][N] f32 -> Wt [L][N][K] bf16 bits
__global__ __launch_bounds__(256) void transcast_kernel(const float* __restrict__ W,
                                                        ushort_t* __restrict__ Wt,
                                                        int K, int Nc) {
    __shared__ float t[32][33];
    const float* Wl = W + (size_t)blockIdx.z*K*Nc;
    ushort_t* Wtl = Wt + (size_t)blockIdx.z*K*Nc;
    int n0 = blockIdx.x*32, k0 = blockIdx.y*32;
    int tx = threadIdx.x & 31, ty = threadIdx.x >> 5;   // 32 x 8
#pragma unroll
    for (int j = 0; j < 32; j += 8)
        t[ty+j][tx] = Wl[(size_t)(k0+ty+j)*Nc + n0+tx];
    __syncthreads();
#pragma unroll
    for (int j = 0; j < 32; j += 8)
        Wtl[(size_t)(n0+ty+j)*K + k0+tx] = f2bf(t[tx][ty+j]);
}

// ---------------------------------------------------------------------------
// LayerNorm: one wave per row of 384; reads f32 X, writes bf16 bits.
__global__ __launch_bounds__(256) void ln_kernel(const float* __restrict__ Xin,
                                                 const float* __restrict__ w,
                                                 const float* __restrict__ bvec,
                                                 ushort_t* __restrict__ out) {
    int wid = threadIdx.x >> 6, lane = threadIdx.x & 63;
    int row = blockIdx.x*4 + wid;
    const float* xr = Xin + (size_t)row*D_;
    float v[6];
#pragma unroll
    for (int i = 0; i < 6; i++) v[i] = xr[lane + i*64];
    float s = 0.f;
#pragma unroll
    for (int i = 0; i < 6; i++) s += v[i];
#pragma unroll
    for (int off = 32; off; off >>= 1) s += __shfl_xor(s, off, 64);
    float mean = s * (1.0f/(float)D_);
    float vs = 0.f;
#pragma unroll
    for (int i = 0; i < 6; i++) { float d = v[i]-mean; vs += d*d; }
#pragma unroll
    for (int off = 32; off; off >>= 1) vs += __shfl_xor(vs, off, 64);
    float var = vs * (1.0f/(float)D_);
    float rstd = 1.0f / sqrtf(var + 1e-5f);
    ushort_t* orow = out + (size_t)row*D_;
#pragma unroll
    for (int i = 0; i < 6; i++) {
        int e = lane + i*64;
        orow[e] = f2bf((v[i]-mean)*rstd*w[e] + bvec[e]);
    }
}

// ---------------------------------------------------------------------------
__device__ __forceinline__ float gelu_f(float x) {
    const float c = 0.7978845608028654f;   // sqrt(2/pi)
    float x3 = x*x*x;
    return 0.5f*x*(1.0f + tanhf(c*(x + 0.044715f*x3)));
}

// ---------------------------------------------------------------------------
// MFMA bf16 GEMM v2 (R5 configuration — LDS stride 32, 16B-aligned b128):
// register-prefetch staging, vectorized epilogues.
// EPI: 0 = bias -> bf16 out; 1 = bias + residual add into f32 C;
//      2 = gelu(bias+acc) -> bf16 out;
//      3 = QKV split: cols<768 packed bf16, cols>=768 scatter to VT.
template<int EPI>
__global__ __launch_bounds__(256) void mfma_gemm(const ushort_t* __restrict__ A,
                                                 const ushort_t* __restrict__ Wt,
                                                 const float* __restrict__ bias,
                                                 void* __restrict__ Cout,
                                                 ushort_t* __restrict__ VT,
                                                 int K, int Nc) {
    __shared__ __attribute__((aligned(16))) ushort_t smem[2*128*32];   // 16 KB
    ushort_t* smA = smem;
    ushort_t* smB = smem + 128*32;
    int tid = threadIdx.x;
    int lane = tid & 63, w = tid >> 6;
    int wm = w >> 1, wn = w & 1;
    int L = lane & 15, G = lane >> 4;
    int rowBase = blockIdx.y * 128, colBase = blockIdx.x * 128;

    floatx4 acc[4][4];
#pragma unroll
    for (int i = 0; i < 4; i++)
#pragma unroll
        for (int j = 0; j < 4; j++) acc[i][j] = (floatx4){0.f,0.f,0.f,0.f};

    // staging map: 256 threads x 2 chunks per buffer; chunk = 16B = 8 bf16
    int sr = tid >> 2;          // row 0..63 (and +64)
    int kc = tid & 3;           // k-chunk 0..3
    const ushort_t* Ag = A  + (size_t)(rowBase + sr)*K + kc*8;
    const ushort_t* Bg = Wt + (size_t)(colBase + sr)*K + kc*8;
    size_t step64 = (size_t)64*K;

    short8 ra0, ra1, rb0, rb1;
    ra0 = *(const short8*)(Ag);
    ra1 = *(const short8*)(Ag + step64);
    rb0 = *(const short8*)(Bg);
    rb1 = *(const short8*)(Bg + step64);

    for (int k0 = 0; k0 < K; k0 += 32) {
        __syncthreads();
        *(short8*)(smA + sr*32 + kc*8)        = ra0;
        *(short8*)(smA + (64+sr)*32 + kc*8)   = ra1;
        *(short8*)(smB + sr*32 + kc*8)        = rb0;
        *(short8*)(smB + (64+sr)*32 + kc*8)   = rb1;
        __syncthreads();
        if (k0 + 32 < K) {      // prefetch next k-slab; loads stay in flight
            ra0 = *(const short8*)(Ag + k0 + 32);
            ra1 = *(const short8*)(Ag + step64 + k0 + 32);
            rb0 = *(const short8*)(Bg + k0 + 32);
            rb1 = *(const short8*)(Bg + step64 + k0 + 32);
        }
        short8 af[4], bfr[4];
#pragma unroll
        for (int t = 0; t < 4; t++) {
            af[t]  = *(const short8*)(smA + (wm*64 + t*16 + L)*32 + G*8);
            bfr[t] = *(const short8*)(smB + (wn*64 + t*16 + L)*32 + G*8);
        }
#pragma unroll
        for (int mt = 0; mt < 4; mt++)
#pragma unroll
            for (int nt = 0; nt < 4; nt++)
                acc[mt][nt] = __builtin_amdgcn_mfma_f32_16x16x32_bf16(
                    af[mt], bfr[nt], acc[mt][nt], 0, 0, 0);
        __syncthreads();
    }

    __syncthreads();   // smem reuse for epilogue

    if (EPI == 3 && colBase >= 2*D_) {
        // pure-V column block: scalar scatter into VT[b,h,d,n]
        int cBase = colBase + wn*64 + L;
        int rBase = rowBase + wm*64 + G*4;
#pragma unroll
        for (int nt = 0; nt < 4; nt++) {
            int col = cBase + nt*16;
            float bv = bias[col];
            int hh = (col - 2*D_) >> 6, d = (col - 2*D_) & 63;
#pragma unroll
            for (int mt = 0; mt < 4; mt++) {
#pragma unroll
                for (int r = 0; r < 4; r++) {
                    int row = rBase + mt*16 + r;
                    int b = row >> 10, n = row & 1023;
                    VT[(((size_t)b*H_ + hh)*64 + d)*N_ + n] = f2bf(acc[mt][nt][r] + bv);
                }
            }
        }
    } else if (EPI == 1) {
        // f32 residual add, vectorized via per-wave LDS slab (16x64 f32)
        float* fs = (float*)smem + w*1024;
        int orow = lane >> 2, c4 = lane & 3;
#pragma unroll
        for (int mt = 0; mt < 4; mt++) {
#pragma unroll
            for (int nt = 0; nt < 4; nt++) {
                float bv = bias[colBase + wn*64 + nt*16 + L];
#pragma unroll
                for (int r = 0; r < 4; r++)
                    fs[(G*4+r)*64 + nt*16 + L] = acc[mt][nt][r] + bv;
            }
            float* og = (float*)Cout + (size_t)(rowBase + wm*64 + mt*16 + orow)*Nc
                        + colBase + wn*64;
#pragma unroll
            for (int kk = 0; kk < 4; kk++) {
                float4 sv = *(float4*)(fs + orow*64 + kk*16 + c4*4);
                float4 gv = *(float4*)(og + kk*16 + c4*4);
                gv.x += sv.x; gv.y += sv.y; gv.z += sv.z; gv.w += sv.w;
                *(float4*)(og + kk*16 + c4*4) = gv;
            }
        }
    } else {
        // bf16 out (EPI 0/2/3-QK), vectorized via per-wave LDS slab (stride 72)
        ushort_t* us = smem + w*1152;
        int orow = lane >> 2, oc = lane & 3;
#pragma unroll
        for (int mt = 0; mt < 4; mt++) {
#pragma unroll
            for (int nt = 0; nt < 4; nt++) {
                float bv = bias[colBase + wn*64 + nt*16 + L];
#pragma unroll
                for (int r = 0; r < 4; r++) {
                    float v = acc[mt][nt][r] + bv;
                    if (EPI == 2) v = gelu_f(v);
                    us[(G*4+r)*72 + nt*16 + L] = f2bf(v);
                }
            }
            short8 o0 = *(short8*)(us + orow*72 + oc*8);
            short8 o1 = *(short8*)(us + orow*72 + 32 + oc*8);
            ushort_t* og = (ushort_t*)Cout + (size_t)(rowBase + wm*64 + mt*16 + orow)*Nc
                           + colBase + wn*64;
            *(short8*)(og + oc*8) = o0;
            *(short8*)(og + 32 + oc*8) = o1;
        }
    }
}

// ---------------------------------------------------------------------------
// Flash attention v2 (R5 configuration): 64-key tiles, register-prefetch
// staging, 2 barriers/tile, wave-private P round-trip, vectorized O store.
// LPAD 72 elements = 144 B (16B-aligned for b128).
#define LPAD 72
__global__ __launch_bounds__(256) void fattn_kernel(const ushort_t* __restrict__ QKV,
                                                    const ushort_t* __restrict__ VT,
                                                    ushort_t* __restrict__ O) {
    __shared__ __attribute__((aligned(16))) ushort_t Ks[64*LPAD];
    __shared__ __attribute__((aligned(16))) ushort_t Vs[64*LPAD];
    __shared__ __attribute__((aligned(16))) ushort_t Pw[4*16*LPAD];
    int b = blockIdx.z, h = blockIdx.y;
    int qBase = blockIdx.x * 64;
    int tid = threadIdx.x;
    int lane = tid & 63, w = tid >> 6;
    int L = lane & 15, G = lane >> 4;

    short8 qf[2];
    {
        const ushort_t* qp = QKV + ((size_t)(b*N_ + qBase + w*16 + L))*DQKV_ + h*HD_ + G*8;
        qf[0] = *(const short8*)(qp);
        qf[1] = *(const short8*)(qp + 32);
    }

    floatx4 oacc[4];
#pragma unroll
    for (int nt = 0; nt < 4; nt++) oacc[nt] = (floatx4){0.f,0.f,0.f,0.f};
    float mrow[4], lrow[4];
#pragma unroll
    for (int r = 0; r < 4; r++) { mrow[r] = -3.0e38f; lrow[r] = 0.f; }

    ushort_t* pw = Pw + w*16*LPAD;
    const ushort_t* Kbase = QKV + (size_t)b*N_*DQKV_ + D_ + h*HD_;
    const ushort_t* Vbase = VT + ((size_t)b*H_ + h)*64*N_;

    // staging map: 512 chunks (16B) per buffer; thread covers chunk tid and tid+256
    int srow = tid >> 3;         // 0..31 (and +32)
    int dc   = tid & 7;
    const ushort_t* Kg0 = Kbase + (size_t)srow*DQKV_ + dc*8;
    const ushort_t* Kg1 = Kbase + (size_t)(srow+32)*DQKV_ + dc*8;
    const ushort_t* Vg0 = Vbase + (size_t)srow*N_ + dc*8;       // srow = d-row for V
    const ushort_t* Vg1 = Vbase + (size_t)(srow+32)*N_ + dc*8;

    short8 rk0, rk1, rv0, rv1;
    rk0 = *(const short8*)(Kg0);
    rk1 = *(const short8*)(Kg1);
    rv0 = *(const short8*)(Vg0);
    rv1 = *(const short8*)(Vg1);

    for (int kt = 0; kt < N_/64; kt++) {
        __syncthreads();   // prior tile's PV reads of Ks/Vs complete
        *(short8*)(Ks + srow*LPAD + dc*8)       = rk0;
        *(short8*)(Ks + (srow+32)*LPAD + dc*8)  = rk1;
        *(short8*)(Vs + srow*LPAD + dc*8)       = rv0;
        *(short8*)(Vs + (srow+32)*LPAD + dc*8)  = rv1;
        __syncthreads();
        if (kt + 1 < N_/64) {   // prefetch next tile (in flight across compute)
            rk0 = *(const short8*)(Kg0 + (size_t)(kt+1)*64*DQKV_);
            rk1 = *(const short8*)(Kg1 + (size_t)(kt+1)*64*DQKV_);
            rv0 = *(const short8*)(Vg0 + (kt+1)*64);
            rv1 = *(const short8*)(Vg1 + (kt+1)*64);
        }

        // S = Q K^T  (16 q-rows x 64 keys per wave)
        floatx4 sc[4];
#pragma unroll
        for (int ct = 0; ct < 4; ct++) sc[ct] = (floatx4){0.f,0.f,0.f,0.f};
#pragma unroll
        for (int ks = 0; ks < 2; ks++)
#pragma unroll
            for (int ct = 0; ct < 4; ct++) {
                short8 bf = *(const short8*)(Ks + (ct*16 + L)*LPAD + ks*32 + G*8);
                sc[ct] = __builtin_amdgcn_mfma_f32_16x16x32_bf16(qf[ks], bf, sc[ct], 0, 0, 0);
            }

        // online softmax over this 64-key tile
        float rmax[4], rsum[4];
#pragma unroll
        for (int r = 0; r < 4; r++) {
#pragma unroll
            for (int ct = 0; ct < 4; ct++) sc[ct][r] *= 0.125f;
            rmax[r] = fmaxf(fmaxf(sc[0][r], sc[1][r]), fmaxf(sc[2][r], sc[3][r]));
        }
#pragma unroll
        for (int off = 1; off < 16; off <<= 1)
#pragma unroll
            for (int r = 0; r < 4; r++) rmax[r] = fmaxf(rmax[r], __shfl_xor(rmax[r], off, 64));
        float corr[4];
#pragma unroll
        for (int r = 0; r < 4; r++) {
            float mn = fmaxf(mrow[r], rmax[r]);
            corr[r] = __expf(mrow[r] - mn);
            mrow[r] = mn;
            rsum[r] = 0.f;
#pragma unroll
            for (int ct = 0; ct < 4; ct++) {
                float p = __expf(sc[ct][r] - mn);
                sc[ct][r] = p;
                rsum[r] += p;
            }
        }
#pragma unroll
        for (int off = 1; off < 16; off <<= 1)
#pragma unroll
            for (int r = 0; r < 4; r++) rsum[r] += __shfl_xor(rsum[r], off, 64);
#pragma unroll
        for (int r = 0; r < 4; r++) lrow[r] = lrow[r]*corr[r] + rsum[r];

        // P (C-layout) -> wave-private LDS -> A-layout (in-wave ordering, no barrier)
#pragma unroll
        for (int ct = 0; ct < 4; ct++)
#pragma unroll
            for (int r = 0; r < 4; r++)
                pw[(G*4 + r)*LPAD + ct*16 + L] = f2bf(sc[ct][r]);
#pragma unroll
        for (int nt = 0; nt < 4; nt++)
#pragma unroll
            for (int r = 0; r < 4; r++) oacc[nt][r] *= corr[r];

        // O += P V
#pragma unroll
        for (int ks = 0; ks < 2; ks++) {
            short8 pf = *(const short8*)(pw + L*LPAD + ks*32 + G*8);
#pragma unroll
            for (int nt = 0; nt < 4; nt++) {
                short8 vf = *(const short8*)(Vs + (nt*16 + L)*LPAD + ks*32 + G*8);
                oacc[nt] = __builtin_amdgcn_mfma_f32_16x16x32_bf16(pf, vf, oacc[nt], 0, 0, 0);
            }
        }
    }

    // normalized O through wave-private pw slab -> vector global store
    float inv[4];
#pragma unroll
    for (int r = 0; r < 4; r++) inv[r] = 1.0f / lrow[r];
#pragma unroll
    for (int nt = 0; nt < 4; nt++)
#pragma unroll
        for (int r = 0; r < 4; r++)
            pw[(G*4 + r)*LPAD + nt*16 + L] = f2bf(oacc[nt][r]*inv[r]);
    int orow = lane >> 2, oc = lane & 3;
    short8 o0 = *(short8*)(pw + orow*LPAD + oc*8);
    short8 o1 = *(short8*)(pw + orow*LPAD + 32 + oc*8);
    ushort_t* og = O + (size_t)(b*N_ + qBase + w*16 + orow)*D_ + h*HD_;
    *(short8*)(og + oc*8) = o0;
    *(short8*)(og + 32 + oc*8) = o1;
}

// ---------------------------------------------------------------------------
// Final projection v2: one wave per row (coalesced); pred[m,c] = X[m,:] @ pw[:,c]
__global__ __launch_bounds__(256) void proj_kernel(const float* __restrict__ X,
                                                   const float* __restrict__ pw,
                                                   float* __restrict__ pred) {
    int wid = threadIdx.x >> 6, lane = threadIdx.x & 63;
    int m = blockIdx.x*4 + wid;
    const float* xr = X + (size_t)m*D_;
    float a0 = 0.f, a1 = 0.f, a2 = 0.f;
#pragma unroll
    for (int i = 0; i < 6; i++) {
        int k = lane + i*64;
        float xv = xr[k];
        a0 += xv*pw[k*3+0]; a1 += xv*pw[k*3+1]; a2 += xv*pw[k*3+2];
    }
#pragma unroll
    for (int off = 32; off; off >>= 1) {
        a0 += __shfl_xor(a0, off, 64);
        a1 += __shfl_xor(a1, off, 64);
        a2 += __shfl_xor(a2, off, 64);
    }
    if (lane == 0) {
        pred[m*3+0] = a0; pred[m*3+1] = a1; pred[m*3+2] = a2;
    }
}

// ---------------------------------------------------------------------------
// FPS v4: 512 threads (8 waves), 16 pts/thread in registers, pts mirrored in
// LDS for winner-coordinate broadcast. One barrier/iter; DS-traffic-minimized:
// per-thread (f32,j) best -> single u64 pack -> 6-round wave reduce ->
// lane-indexed slot read + 3-round in-wave merge.
__global__ __launch_bounds__(512) void fps_kernel(const float* __restrict__ pts,
                                                  float* __restrict__ centers) {
    __shared__ float Lx[P_], Ly[P_], Lz[P_];            // 96 KiB
    __shared__ u64_t slot[2][8];
    int b = blockIdx.x, t = threadIdx.x;
    const float* pb = pts + (size_t)b*P_*3;
    float px[16], py[16], pz[16], dist[16];
#pragma unroll
    for (int j = 0; j < 16; j++) {
        int p = j*512 + t;
        px[j] = pb[p*3+0]; py[j] = pb[p*3+1]; pz[j] = pb[p*3+2];
        Lx[p] = px[j]; Ly[p] = py[j]; Lz[p] = pz[j];
        dist[j] = 1e10f;
    }
    int wid = t >> 6, lane = t & 63;
    int winner = 0;
    __syncthreads();
    for (int it = 0; it < N_; it++) {
        float lx = Lx[winner], ly = Ly[winner], lz = Lz[winner];
        if (t == 0) {
            float* c = centers + ((size_t)b*N_ + it)*3;
            c[0] = lx; c[1] = ly; c[2] = lz;
        }
        // per-thread best: strict > with ascending j == smallest index on ties
        float bd = -1.0f; int bj = 0;
#pragma unroll
        for (int j = 0; j < 16; j++) {
            float dx = __fsub_rn(px[j], lx);
            float dy = __fsub_rn(py[j], ly);
            float dz = __fsub_rn(pz[j], lz);
            float d = __fadd_rn(__fadd_rn(__fmul_rn(dx,dx), __fmul_rn(dy,dy)), __fmul_rn(dz,dz));
            d = fminf(dist[j], d);
            dist[j] = d;
            bool gt = d > bd;
            bd = gt ? d : bd;
            bj = gt ? j : bj;
        }
        // pack once: global idx = bj*512 + t (ascending in j), ~idx -> first-wins
        u64_t best = ((u64_t)__float_as_uint(bd) << 32)
                   | (unsigned)(~(unsigned)(bj*512 + t));
#pragma unroll
        for (int off = 32; off; off >>= 1) {
            u64_t o = __shfl_xor(best, off, 64);
            best = (o > best) ? o : best;
        }
        int par = it & 1;
        if (lane == 0) slot[par][wid] = best;
        __syncthreads();
        // merge 8 wave maxima: lane-indexed read + 3 xor rounds (all lanes agree)
        u64_t v = slot[par][lane & 7];
#pragma unroll
        for (int off = 1; off < 8; off <<= 1) {
            u64_t o = __shfl_xor(v, off, 64);
            v = (o > v) ? o : v;
        }
        winner = (int)(~(unsigned)(v & 0xFFFFFFFFull));
    }
}

// ---------------------------------------------------------------------------
__global__ __launch_bounds__(256) void nnmin_kernel(const float* __restrict__ Asrc,
                                                    const float* __restrict__ Bsrc,
                                                    float* __restrict__ outmin) {
    int b = blockIdx.y;
    int i = blockIdx.x*256 + threadIdx.x;
    __shared__ float tile[256][3];
    const float* ar = Asrc + ((size_t)b*N_ + i)*3;
    float ax = ar[0], ay = ar[1], az = ar[2];
    float best = 3.0e38f;
    for (int j0 = 0; j0 < N_; j0 += 256) {
        __syncthreads();
        const float* br = Bsrc + ((size_t)b*N_ + j0 + threadIdx.x)*3;
        tile[threadIdx.x][0] = br[0]; tile[threadIdx.x][1] = br[1]; tile[threadIdx.x][2] = br[2];
        __syncthreads();
        for (int j = 0; j < 256; j++) {
            float dx = ax - tile[j][0], dy = ay - tile[j][1], dz = az - tile[j][2];
            float d = dx*dx + dy*dy + dz*dz;
            best = fminf(best, d);
        }
    }
    outmin[(size_t)b*N_ + i] = sqrtf(best);
}

__global__ __launch_bounds__(256) void knn_kernel(const float* __restrict__ Pp,
                                                  float* __restrict__ mean_d) {
    int b = blockIdx.y;
    int i = blockIdx.x*256 + threadIdx.x;
    __shared__ float tile[256][3];
    const float* ar = Pp + ((size_t)b*N_ + i)*3;
    float ax = ar[0], ay = ar[1], az = ar[2];
    float s[6];
#pragma unroll
    for (int q = 0; q < 6; q++) s[q] = 3.0e38f;
    for (int j0 = 0; j0 < N_; j0 += 256) {
        __syncthreads();
        const float* br = Pp + ((size_t)b*N_ + j0 + threadIdx.x)*3;
        tile[threadIdx.x][0] = br[0]; tile[threadIdx.x][1] = br[1]; tile[threadIdx.x][2] = br[2];
        __syncthreads();
        for (int j = 0; j < 256; j++) {
            float dx = ax - tile[j][0], dy = ay - tile[j][1], dz = az - tile[j][2];
            float d = dx*dx + dy*dy + dz*dz;
            if (d < s[5]) {
                s[5] = d;
#pragma unroll
                for (int q = 5; q > 0; q--)
                    if (s[q] < s[q-1]) { float tmp = s[q]; s[q] = s[q-1]; s[q-1] = tmp; }
            }
        }
    }
    float msum = sqrtf(s[1]) + sqrtf(s[2]) + sqrtf(s[3]) + sqrtf(s[4]) + sqrtf(s[5]);
    mean_d[(size_t)b*N_ + i] = msum * 0.2f;
}

__global__ __launch_bounds__(256) void kl_kernel(const float* __restrict__ md,
                                                 float* __restrict__ klb) {
    int b = blockIdx.x, t = threadIdx.x;
    const float* row = md + (size_t)b*N_;
    float v[4];
#pragma unroll
    for (int i = 0; i < 4; i++) v[i] = row[t + i*256];
    float mx = fmaxf(fmaxf(v[0], v[1]), fmaxf(v[2], v[3]));
#pragma unroll
    for (int off = 32; off; off >>= 1) mx = fmaxf(mx, __shfl_xor(mx, off, 64));
    __shared__ float redm[4], rse[4], rsx[4];
    int wid = t >> 6, lane = t & 63;
    if (lane == 0) redm[wid] = mx;
    __syncthreads();
    mx = fmaxf(fmaxf(redm[0], redm[1]), fmaxf(redm[2], redm[3]));
    float se = 0.f, sx = 0.f;
#pragma unroll
    for (int i = 0; i < 4; i++) { se += expf(v[i]-mx); sx += v[i]; }
#pragma unroll
    for (int off = 32; off; off >>= 1) { se += __shfl_xor(se, off, 64); sx += __shfl_xor(sx, off, 64); }
    if (lane == 0) { rse[wid] = se; rsx[wid] = sx; }
    __syncthreads();
    if (t == 0) {
        float SE = rse[0]+rse[1]+rse[2]+rse[3];
        float SX = rsx[0]+rsx[1]+rsx[2]+rsx[3];
        klb[b] = mx + logf(SE) - SX*(1.0f/(float)N_) - logf((float)N_);
    }
}

__global__ __launch_bounds__(256) void final_kernel(const float* __restrict__ rma,
                                                    const float* __restrict__ rmb,
                                                    const float* __restrict__ klb,
                                                    float* __restrict__ out) {
    int t = threadIdx.x;
    float s = 0.f;
    for (int i = t; i < B_*N_; i += 256) s += rma[i] + rmb[i];
#pragma unroll
    for (int off = 32; off; off >>= 1) s += __shfl_xor(s, off, 64);
    __shared__ float red[4];
    int wid = t >> 6, lane = t & 63;
    if (lane == 0) red[wid] = s;
    __syncthreads();
    if (t == 0) {
        float S = red[0]+red[1]+red[2]+red[3];
        out[0] = 0.5f*S/(float)(B_*N_);
        float K = 0.f;
        for (int b = 0; b < B_; b++) K += klb[b];
        out[1] = K/(float)B_;
    }
}

// ---------------------------------------------------------------------------
extern "C" void kernel_launch(void* const* d_in, const int* in_sizes, int n_in,
                              void* d_out, int out_size, void* d_ws, size_t ws_size,
                              hipStream_t stream) {
    (void)in_sizes; (void)n_in; (void)out_size; (void)ws_size;
    const float* pts     = (const float*)d_in[0];
    const float* grid    = (const float*)d_in[1];
    const float* embed_w = (const float*)d_in[2];
    const float* proj_w  = (const float*)d_in[3];
    const float* ln1_w   = (const float*)d_in[4];
    const float* ln1_b   = (const float*)d_in[5];
    const float* qkv_w   = (const float*)d_in[6];
    const float* qkv_b   = (const float*)d_in[7];
    const float* attn_w  = (const float*)d_in[8];
    const float* attn_b  = (const float*)d_in[9];
    const float* ln2_w   = (const float*)d_in[10];
    const float* ln2_b   = (const float*)d_in[11];
    const float* mlp_w1  = (const float*)d_in[12];
    const float* mlp_b1  = (const float*)d_in[13];
    const float* mlp_w2  = (const float*)d_in[14];
    const float* mlp_b2  = (const float*)d_in[15];
    float* out = (float*)d_out;

    // workspace layout (~144 MB)
    float*    X     = (float*)d_ws;                         // M*D f32
    ushort_t* Hb16  = (ushort_t*)(X + (size_t)M_*D_);       // M*D bf16
    ushort_t* BIG16 = Hb16 + (size_t)M_*D_;                 // M*1536 bf16 (QKV / MLP hidden)
    ushort_t* VT    = BIG16 + (size_t)M_*DH_;               // B*H*64*N bf16 (V transposed)
    ushort_t* WQ    = VT  + (size_t)B_*H_*HD_*N_;           // L*1152*384
    ushort_t* WA    = WQ  + (size_t)L_*DQKV_*D_;            // L*384*384
    ushort_t* WM1   = WA  + (size_t)L_*D_*D_;               // L*1536*384
    ushort_t* WM2   = WM1 + (size_t)L_*DH_*D_;              // L*384*1536
    float*    PRED  = (float*)(WM2 + (size_t)L_*D_*DH_);    // M*3
    float*    CENT  = PRED + (size_t)M_*3;                  // B*N*3
    float*    RMA   = CENT + (size_t)B_*N_*3;               // B*N
    float*    RMB   = RMA  + (size_t)B_*N_;                 // B*N
    float*    MEAND = RMB  + (size_t)B_*N_;                 // B*N
    float*    KLB   = MEAND + (size_t)B_*N_;                // B

    // one-time weight transpose-casts (f32 [K,N] -> bf16 [N,K])
    transcast_kernel<<<dim3(DQKV_/32, D_/32,  L_), 256, 0, stream>>>(qkv_w,  WQ,  D_,  DQKV_);
    transcast_kernel<<<dim3(D_/32,    D_/32,  L_), 256, 0, stream>>>(attn_w, WA,  D_,  D_);
    transcast_kernel<<<dim3(DH_/32,   D_/32,  L_), 256, 0, stream>>>(mlp_w1, WM1, D_,  DH_);
    transcast_kernel<<<dim3(D_/32,    DH_/32, L_), 256, 0, stream>>>(mlp_w2, WM2, DH_, D_);

    // FPS (independent of transformer)
    fps_kernel<<<B_, 512, 0, stream>>>(pts, CENT);

    embed_kernel<<<M_, D_, 0, stream>>>(grid, embed_w, X);

    for (int l = 0; l < L_; l++) {
        ln_kernel<<<M_/4, 256, 0, stream>>>(X, ln1_w + l*D_, ln1_b + l*D_, Hb16);
        mfma_gemm<3><<<dim3(DQKV_/128, M_/128), 256, 0, stream>>>(
            Hb16, WQ + (size_t)l*DQKV_*D_, qkv_b + l*DQKV_, BIG16, VT, D_, DQKV_);
        fattn_kernel<<<dim3(N_/64, H_, B_), 256, 0, stream>>>(BIG16, VT, Hb16);
        mfma_gemm<1><<<dim3(D_/128, M_/128), 256, 0, stream>>>(
            Hb16, WA + (size_t)l*D_*D_, attn_b + l*D_, X, nullptr, D_, D_);
        ln_kernel<<<M_/4, 256, 0, stream>>>(X, ln2_w + l*D_, ln2_b + l*D_, Hb16);
        mfma_gemm<2><<<dim3(DH_/128, M_/128), 256, 0, stream>>>(
            Hb16, WM1 + (size_t)l*DH_*D_, mlp_b1 + l*DH_, BIG16, nullptr, D_, DH_);
        mfma_gemm<1><<<dim3(D_/128, M_/128), 256, 0, stream>>>(
            BIG16, WM2 + (size_t)l*D_*DH_, mlp_b2 + l*D_, X, nullptr, DH_, D_);
    }

    proj_kernel<<<M_/4, 256, 0, stream>>>(X, proj_w, PRED);

    nnmin_kernel<<<dim3(N_/256, B_), 256, 0, stream>>>(PRED, CENT, RMA);
    nnmin_kernel<<<dim3(N_/256, B_), 256, 0, stream>>>(CENT, PRED, RMB);
    knn_kernel<<<dim3(N_/256, B_), 256, 0, stream>>>(PRED, MEAND);
    kl_kernel<<<B_, 256, 0, stream>>>(MEAND, KLB);
    final_kernel<<<1, 256, 0, stream>>>(RMA, RMB, KLB, out);
}